// Round 16
// baseline (248.095 us; speedup 1.0000x reference)
//
#include <hip/hip_runtime.h>
#include <hip/hip_bf16.h>
#include <math.h>

// StyleGAN3 SynthesisLayer forward, MI355X.
// B=16, CIN=COUT=256, H=W=64, K=3, up=2 down=2 taps=12, conv out 66x66,
// up-FIR out 138x138, final out 64x64.

typedef __attribute__((ext_vector_type(8))) short bf16x8;
typedef __attribute__((ext_vector_type(4))) float f32x4;
typedef _Float16 h2 __attribute__((ext_vector_type(2)));

#define NM 69696         // 16*66*66 flattened conv-output positions
#define SPI 4356         // 66*66 spatial per image

__device__ inline void gload16(const void* g, void* l) {
  __builtin_amdgcn_global_load_lds((const __attribute__((address_space(1))) void*)g,
                                   (__attribute__((address_space(3))) void*)l, 16, 0, 0);
}
static __device__ __forceinline__ short f2hs(float f) {
  _Float16 h = (_Float16)f;
  return *(short*)&h;
}
static __device__ __forceinline__ h2 h2bc(unsigned u) { return __builtin_bit_cast(h2, u); }
static __device__ __forceinline__ unsigned u32bc(h2 v) { return __builtin_bit_cast(unsigned, v); }
static __device__ __forceinline__ h2 h2splat(float f) {
  _Float16 x = (_Float16)f; h2 r; r[0] = x; r[1] = x; return r;
}

// ---------- styles = w @ aw^T / sqrt(512) + ab ----------
__global__ __launch_bounds__(256) void k_styles(
    const float* __restrict__ w, const float* __restrict__ aw,
    const float* __restrict__ ab, float* __restrict__ styles) {
  __shared__ float lw[512];
  int b = blockIdx.x, t = threadIdx.x;
  lw[t] = w[b * 512 + t];
  lw[t + 256] = w[b * 512 + t + 256];
  __syncthreads();
  const float* row = aw + (long)t * 512;
  float acc = 0.f;
  #pragma unroll 4
  for (int d = 0; d < 512; ++d) acc += row[d] * lw[d];
  styles[b * 256 + t] = acc * 0.04419417382415922f + ab[t];
}

// ---------- scal[0] = 1/mean(styles^2), scal[1] = rsqrt(ema) ----------
__global__ __launch_bounds__(256) void k_scalars(
    const float* __restrict__ styles, const float* __restrict__ ema,
    float* __restrict__ scal) {
  __shared__ float red[256];
  int t = threadIdx.x;
  float s = 0.f;
  #pragma unroll
  for (int k = 0; k < 16; ++k) { float v = styles[t + k * 256]; s += v * v; }
  red[t] = s; __syncthreads();
  for (int off = 128; off > 0; off >>= 1) {
    if (t < off) red[t] += red[t + off];
    __syncthreads();
  }
  if (t == 0) { scal[0] = 4096.0f / red[0]; scal[1] = 1.0f / sqrtf(ema[0]); }
}

// ---------- per-o weight norm; wsq[o][i]; wbt[tap][o][i] bf16 ----------
__global__ __launch_bounds__(256) void k_wnorm(
    const float* __restrict__ cw, float* __restrict__ wsq,
    __hip_bfloat16* __restrict__ wbt) {
  __shared__ float red[256];
  __shared__ float lws, lws2;
  int o = blockIdx.x, t = threadIdx.x;
  const float* base = cw + o * 2304;
  float s = 0.f;
  #pragma unroll
  for (int k = 0; k < 9; ++k) { float v = base[t + k * 256]; s += v * v; }
  red[t] = s; __syncthreads();
  for (int off = 128; off > 0; off >>= 1) {
    if (t < off) red[t] += red[t + off];
    __syncthreads();
  }
  if (t == 0) { lws2 = 2304.0f / red[0]; lws = sqrtf(lws2); }
  __syncthreads();
  const float* r9 = base + t * 9;
  float s9 = 0.f;
  #pragma unroll
  for (int k = 0; k < 9; ++k) s9 += r9[k] * r9[k];
  wsq[o * 256 + t] = lws2 * s9;
  #pragma unroll
  for (int tap = 0; tap < 9; ++tap)
    wbt[(tap * 256 + o) * 256 + t] = __float2bfloat16(r9[tap] * lws);
}

// ---------- dcoefs[b][o] = rsqrt(sum_i s^2 * wsq + 1e-8) * input_gain ----------
__global__ __launch_bounds__(256) void k_dcoefs(
    const float* __restrict__ styles, const float* __restrict__ wsq,
    const float* __restrict__ scal, float* __restrict__ dco) {
  __shared__ float sn2[256];
  int b = blockIdx.x, t = threadIdx.x;
  float v = styles[b * 256 + t];
  sn2[t] = v * v * scal[0];
  __syncthreads();
  const float* wr = wsq + t * 256;
  float acc = 0.f;
  #pragma unroll 4
  for (int i = 0; i < 256; ++i) acc += sn2[i] * wr[i];
  dco[b * 256 + t] = (1.0f / sqrtf(acc + 1e-8f)) * scal[1];
}

// ---------- xs_pad[b][68][68][256] bf16, NHWC, style-scaled ----------
__global__ __launch_bounds__(256) void k_xpad(
    const float* __restrict__ x, const float* __restrict__ styles,
    const float* __restrict__ scal, unsigned short* __restrict__ xp) {
  __shared__ float lx[64 * 65];
  __shared__ float sc[64];
  int ig = blockIdx.x, hp = blockIdx.y, b = blockIdx.z, t = threadIdx.x;
  int i0 = ig * 64;
  float ss = sqrtf(scal[0]);
  if (t < 64) sc[t] = styles[b * 256 + i0 + t] * ss;
  int h = hp - 2;
  bool inh = (hp >= 2) && (hp < 66);
  if (inh) {
    #pragma unroll
    for (int p = 0; p < 16; ++p) {
      int idx = p * 256 + t; int i = idx >> 6, w = idx & 63;
      lx[i * 65 + w] = x[((b * 256 + i0 + i) * 64 + h) * 64 + w];
    }
  }
  __syncthreads();
  unsigned short* dst = xp + ((long)(b * 68 + hp) * 68) * 256 + i0;
  #pragma unroll
  for (int p = 0; p < 17; ++p) {
    int idx = p * 256 + t; int wp = idx >> 6, i = idx & 63;
    float v = 0.f;
    if (inh && wp >= 2 && wp < 66) v = lx[i * 65 + (wp - 2)] * sc[i];
    __hip_bfloat16 bv = __float2bfloat16(v);
    dst[wp * 256 + i] = *(unsigned short*)&bv;
  }
}

// ---------- conv v8b: BN=64 + launch_bounds(256,6) ----------
// R14 diagnosis: at 5 blocks/CU this kernel runs ~87% of LDS peak BW
// (73KB LDS traffic per block-step; reads already at the 4-wave tiling
// minimum). Only remaining non-structural lever: residency. (256,6):
// V44+A32=76 regs <= 85 (512/6), LDS 24KB*6=144 <= 160 -> 6 blocks/CU.
__global__ __launch_bounds__(256, 6) void k_conv(
    const unsigned short* __restrict__ xp, const unsigned short* __restrict__ wbt,
    const float* __restrict__ dco, const float* __restrict__ bias,
    unsigned short* __restrict__ y) {
  __shared__ __align__(16) unsigned short As[128 * 64];   // 16 KB
  __shared__ __align__(16) unsigned short Bs[64 * 64];    // 8 KB
  const int t = threadIdx.x;
  const int lane = t & 63;
  const int wave = t >> 6;
  const int wm = wave >> 1, wn = wave & 1;   // 2m x 2n

  // bijective XCD swizzle: nwg=2180 = 8*272 + 4 (xcd 0..3 get 273)
  const int f = blockIdx.x;
  const int xcd = f & 7, pos = f >> 3;
  const int wgid = (xcd < 4 ? xcd * 273 : 1092 + (xcd - 4) * 272) + pos;
  const int o0 = (wgid & 3) * 64;
  const int m0 = (wgid >> 2) * 128;

  // A staging (identical to R1): 1024 slots, 4/thread
  int abase[4];
  #pragma unroll
  for (int j = 0; j < 4; ++j) {
    int task = j * 256 + t;
    int lm = task >> 3, ch = task & 7;
    int csrc = ch ^ (lm & 7);
    int m = m0 + lm; if (m > NM - 1) m = NM - 1;
    int b = m / SPI; int sp = m - b * SPI;
    int r = sp / 66; int c = sp - r * 66;
    abase[j] = (((b * 68 + r) * 68 + c) << 9) + (csrc << 4);   // bytes
  }
  // B staging: 512 slots (64 o-rows x 8 chunks), 2/thread
  int bbase[2];
  #pragma unroll
  for (int j = 0; j < 2; ++j) {
    int task = j * 256 + t;
    int lm = task >> 3, ch = task & 7;
    int csrc = ch ^ (lm & 7);
    bbase[j] = ((o0 + lm) << 9) + (csrc << 4);                 // bytes
  }
  f32x4 acc[4][2] = {};
  const char* xb = (const char*)xp;
  const char* wb = (const char*)wbt;
  char* asb = (char*)As;
  char* bsb = (char*)Bs;

  for (int kk = 0; kk < 36; ++kk) {
    int tap = kk >> 2;
    int ch0b = (kk & 3) << 7;            // ch0 * 2 bytes
    int ky = tap / 3, kx = tap - ky * 3;
    int aoff = ((ky * 68 + kx) << 9) + ch0b;
    int boff = (tap << 17) + ch0b;
    #pragma unroll
    for (int j = 0; j < 4; ++j)
      gload16(xb + abase[j] + aoff, asb + ((j * 256 + t) << 4));
    #pragma unroll
    for (int j = 0; j < 2; ++j)
      gload16(wb + bbase[j] + boff, bsb + ((j * 256 + t) << 4));
    __syncthreads();   // drains vmcnt -> tiles visible
    #pragma unroll
    for (int h = 0; h < 2; ++h) {
      bf16x8 av[4], bv[2];
      #pragma unroll
      for (int fm = 0; fm < 4; ++fm) {
        int arow = wm * 64 + fm * 16 + (lane & 15);
        int chk = ((h << 2) + (lane >> 4)) ^ (arow & 7);
        av[fm] = *(const bf16x8*)(asb + arow * 128 + chk * 16);
      }
      #pragma unroll
      for (int fn = 0; fn < 2; ++fn) {
        int brow = wn * 32 + fn * 16 + (lane & 15);
        int chk = ((h << 2) + (lane >> 4)) ^ (brow & 7);
        bv[fn] = *(const bf16x8*)(bsb + brow * 128 + chk * 16);
      }
      #pragma unroll
      for (int fm = 0; fm < 4; ++fm)
        #pragma unroll
        for (int fn = 0; fn < 2; ++fn)
          acc[fm][fn] = __builtin_amdgcn_mfma_f32_16x16x32_bf16(
              av[fm], bv[fn], acc[fm][fn], 0, 0, 0);
    }
    __syncthreads();   // readers done before next overwrite
  }

  // Epilogue: scale + bias, transpose via LDS slab [128m][17], write NCHW fp16.
  float* slab = (float*)As;
  #pragma unroll
  for (int s = 0; s < 4; ++s) {
    if (wn == (s >> 1)) {
      const int sfn = s & 1;
      int ocol = lane & 15;
      int og = o0 + s * 16 + ocol;
      float bo = bias[og];
      #pragma unroll
      for (int fm = 0; fm < 4; ++fm) {
        #pragma unroll
        for (int j = 0; j < 4; ++j) {
          int lm = wm * 64 + fm * 16 + ((lane >> 4) << 2) + j;
          int m = m0 + lm;
          float v = acc[fm][sfn][j];
          if (m < NM) {
            int b = m / SPI;
            v = v * dco[b * 256 + og] + bo;
          }
          slab[lm * 17 + ocol] = v;
        }
      }
    }
    __syncthreads();
    int oc2 = t >> 4;
    int og2 = o0 + s * 16 + oc2;
    #pragma unroll
    for (int p = 0; p < 8; ++p) {
      int lm = (t & 15) + p * 16;
      int m = m0 + lm;
      if (m < NM) {
        int b = m / SPI; int sp = m - b * SPI;
        y[(long)(b * 256 + og2) * SPI + sp] =
            (unsigned short)f2hs(slab[lm * 17 + oc2]);
      }
    }
    __syncthreads();
  }
}

// ---------- filtered_lrelu v4b: fp16 packed datapath (R13, unchanged) ----------
struct Filt { float f[12]; };

__global__ __launch_bounds__(256) void k_lrelu(
    const unsigned short* __restrict__ y, float* __restrict__ out, Filt ft) {
  __shared__ __align__(16) short t1s[138 * 40];   // 11040 B
  __shared__ __align__(16) short t2s[138 * 56];   // 15456 B
  short* bufYs = t2s;                             // [78][56]
  short* t3s = t1s;                               // [64][56]
  const int t = threadIdx.x;
  const int strip = blockIdx.x & 3;
  const long img = blockIdx.x >> 2;
  const int c0 = strip * 16;
  const unsigned short* ysrc = y + img * SPI;

  const h2 z2 = h2splat(0.f);
  h2 e2[6], o2[6], c3[6], c4[12];
  #pragma unroll
  for (int j = 0; j < 6; ++j) {
    e2[j] = h2splat(2.f * ft.f[2 * j]);
    o2[j] = h2splat(2.f * ft.f[2 * j + 1]);
    h2 c; c[0] = (_Float16)(2.f * ft.f[2 * j + 1]); c[1] = (_Float16)(2.f * ft.f[2 * j]);
    c3[j] = c;
  }
  #pragma unroll
  for (int j = 0; j < 12; ++j) c4[j] = h2splat(ft.f[j]);
  const h2 k02 = h2splat(0.2f);
  const h2 ks2 = h2splat(1.41421356237f);
  const h2 kpc = h2splat(256.f);
  const h2 knc = h2splat(-256.f);

  // phase 1: bufY [78][56] fp16; rows 6..71 = y rows 0..65; cols c0-4..c0+21
  #pragma unroll
  for (int p = 0; p < 2; ++p) {
    int e = p * 256 + t;
    if (e < 312) {
      int rp = e >> 2, cg = e & 3;
      int r = rp - 6;
      int cbase = c0 - 4 + 8 * cg;
      uint4 pk = make_uint4(0u, 0u, 0u, 0u);
      if (r >= 0 && r < 66) {
        if (cg < 3 && cbase >= 0 && cbase + 7 <= 65) {
          pk = *(const uint4*)(ysrc + r * 66 + cbase);
        } else {
          unsigned v[8];
          #pragma unroll
          for (int k = 0; k < 8; ++k) {
            int lc = 8 * cg + k, c = c0 - 4 + lc;
            v[k] = (lc < 26 && c >= 0 && c < 66) ? (unsigned)ysrc[r * 66 + c] : 0u;
          }
          pk.x = v[0] | (v[1] << 16); pk.y = v[2] | (v[3] << 16);
          pk.z = v[4] | (v[5] << 16); pk.w = v[6] | (v[7] << 16);
        }
      }
      *(uint4*)(bufYs + rp * 56 + 8 * cg) = pk;
    }
  }
  __syncthreads();

  // phase 2: vertical up-FIR, row pairs -> t1 [138][40]
  #pragma unroll
  for (int p = 0; p < 2; ++p) {
    int e = p * 256 + t;
    if (e < 276) {
      int rq = e >> 2, cg = e & 3;
      const short* base = bufYs + (rq + 2) * 56 + 8 * cg;
      h2 a0[4], a1[4];
      #pragma unroll
      for (int k = 0; k < 4; ++k) { a0[k] = z2; a1[k] = z2; }
      #pragma unroll
      for (int j = 0; j < 6; ++j) {
        uint4 u = *(const uint4*)(base + j * 56);
        h2 v0 = h2bc(u.x), v1 = h2bc(u.y), v2 = h2bc(u.z), v3 = h2bc(u.w);
        a0[0] = v0 * o2[j] + a0[0]; a1[0] = v0 * e2[j] + a1[0];
        a0[1] = v1 * o2[j] + a0[1]; a1[1] = v1 * e2[j] + a1[1];
        a0[2] = v2 * o2[j] + a0[2]; a1[2] = v2 * e2[j] + a1[2];
        a0[3] = v3 * o2[j] + a0[3]; a1[3] = v3 * e2[j] + a1[3];
      }
      uint4 s0, s1;
      s0.x = u32bc(a0[0]); s0.y = u32bc(a0[1]); s0.z = u32bc(a0[2]); s0.w = u32bc(a0[3]);
      s1.x = u32bc(a1[0]); s1.y = u32bc(a1[1]); s1.z = u32bc(a1[2]); s1.w = u32bc(a1[3]);
      *(uint4*)(t1s + (2 * rq) * 40 + 8 * cg) = s0;
      *(uint4*)(t1s + (2 * rq + 1) * 40 + 8 * cg) = s1;
    }
  }
  __syncthreads();

  // phase 3: horizontal up-FIR + lrelu*sqrt2 + clamp -> t2 [138][56]
  #pragma unroll
  for (int p = 0; p < 4; ++p) {
    int e = p * 256 + t;
    if (e < 828) {
      int rr = e / 6, g = e - rr * 6;
      const short* tr = t1s + rr * 40 + 4 * g;
      h2 h[5];
      #pragma unroll
      for (int q = 0; q < 5; ++q) h[q] = h2bc(*(const unsigned*)(tr + 2 * q));
      h2 r[4];
      #pragma unroll
      for (int i = 0; i < 4; ++i) {
        h2 a = z2;
        #pragma unroll
        for (int j = 0; j < 6; ++j) {
          int k = i + j;
          h2 src = h[k >> 1];
          h2 wb = (k & 1) ? __builtin_shufflevector(src, src, 1, 1)
                          : __builtin_shufflevector(src, src, 0, 0);
          a = wb * c3[j] + a;
        }
        h2 m = __builtin_elementwise_max(a, a * k02);
        m = m * ks2;
        m = __builtin_elementwise_min(__builtin_elementwise_max(m, knc), kpc);
        r[i] = m;
      }
      uint4 s;
      s.x = u32bc(r[0]); s.y = u32bc(r[1]); s.z = u32bc(r[2]); s.w = u32bc(r[3]);
      *(uint4*)(t2s + rr * 56 + 8 * g) = s;
    }
  }
  __syncthreads();

  // phase 4: vertical down-FIR (stride 2) -> t3 [64][56]
  #pragma unroll
  for (int p = 0; p < 2; ++p) {
    int e = p * 256 + t;
    if (e < 384) {
      int pp = e / 6, cg = e - pp * 6;
      const short* col = t2s + (2 * pp) * 56 + 8 * cg;
      h2 a[4];
      #pragma unroll
      for (int k = 0; k < 4; ++k) a[k] = z2;
      #pragma unroll
      for (int j = 0; j < 12; ++j) {
        uint4 u = *(const uint4*)(col + j * 56);
        a[0] = h2bc(u.x) * c4[j] + a[0];
        a[1] = h2bc(u.y) * c4[j] + a[1];
        a[2] = h2bc(u.z) * c4[j] + a[2];
        a[3] = h2bc(u.w) * c4[j] + a[3];
      }
      uint4 s;
      s.x = u32bc(a[0]); s.y = u32bc(a[1]); s.z = u32bc(a[2]); s.w = u32bc(a[3]);
      *(uint4*)(t3s + pp * 56 + 8 * cg) = s;
    }
  }
  __syncthreads();

  // phase 5: horizontal down-FIR (stride 2) + store f32, 4 outs/thread
  {
    int pp = t >> 2, v = t & 3;
    const short* row = t3s + pp * 56 + 8 * v;
    h2 h[9];
    #pragma unroll
    for (int q = 0; q < 9; ++q) h[q] = h2bc(*(const unsigned*)(row + 2 * q));
    h2 aA = z2, aB = z2;
    #pragma unroll
    for (int j = 0; j < 12; ++j) {
      int q = j >> 1;
      h2 wA = (j & 1) ? __builtin_shufflevector(h[q], h[q + 1], 1, 3)
                      : __builtin_shufflevector(h[q], h[q + 1], 0, 2);
      h2 wB = (j & 1) ? __builtin_shufflevector(h[q + 2], h[q + 3], 1, 3)
                      : __builtin_shufflevector(h[q + 2], h[q + 3], 0, 2);
      aA = wA * c4[j] + aA;
      aB = wB * c4[j] + aB;
    }
    *(float4*)&out[img * 4096 + pp * 64 + c0 + 4 * v] =
        make_float4((float)aA[0], (float)aA[1], (float)aB[0], (float)aB[1]);
  }
}

// ---------- host ----------
static double bessel_i0(double x) {
  double q = x * x * 0.25, term = 1.0, sum = 1.0;
  for (int k = 1; k < 64; ++k) {
    term *= q / ((double)k * (double)k);
    sum += term;
    if (term < sum * 1e-18) break;
  }
  return sum;
}

extern "C" void kernel_launch(void* const* d_in, const int* in_sizes, int n_in,
                              void* d_out, int out_size, void* d_ws, size_t ws_size,
                              hipStream_t stream) {
  const float* x   = (const float*)d_in[0];
  const float* w   = (const float*)d_in[1];
  const float* aw  = (const float*)d_in[2];
  const float* ab  = (const float*)d_in[3];
  const float* cw  = (const float*)d_in[4];
  const float* cb  = (const float*)d_in[5];
  const float* ema = (const float*)d_in[6];
  float* out = (float*)d_out;
  char* ws = (char*)d_ws;

  float* styles        = (float*)(ws + 0);          // 16 KB
  float* scal          = (float*)(ws + 16384);      // 16 B
  float* wsq           = (float*)(ws + 16640);      // 256 KB
  float* dco           = (float*)(ws + 278784);     // 16 KB
  __hip_bfloat16* wbt  = (__hip_bfloat16*)(ws + 295168);   // 1.18 MB  [9][256][256]
  unsigned short* xp   = (unsigned short*)(ws + 1474816);  // 37.9 MB  [16][68][68][256]
  unsigned short* y    = (unsigned short*)(ws + 39354624); // 35.7 MB  [16][256][66][66] fp16

  // firwin(12, 16, width=32, fs=128) with Kaiser window (double precision)
  Filt ft;
  {
    double atten = 2.285 * 11.0 * M_PI * 0.5 + 7.95;
    double beta;
    if (atten > 50.0) beta = 0.1102 * (atten - 8.7);
    else if (atten > 21.0) beta = 0.5842 * pow(atten - 21.0, 0.4) + 0.07886 * (atten - 21.0);
    else beta = 0.0;
    double i0b = bessel_i0(beta);
    double h[12], ssum = 0.0;
    for (int n = 0; n < 12; ++n) {
      double xx = ((double)n - 5.5) / 5.5;
      double win = bessel_i0(beta * sqrt(1.0 - xx * xx)) / i0b;
      double mm = ((double)n - 5.5) * 0.25;
      double snc = sin(M_PI * mm) / (M_PI * mm);
      h[n] = 0.25 * snc * win;
      ssum += h[n];
    }
    for (int n = 0; n < 12; ++n) ft.f[n] = (float)(h[n] / ssum);
  }

  k_styles <<<16, 256, 0, stream>>>(w, aw, ab, styles);
  k_scalars<<<1, 256, 0, stream>>>(styles, ema, scal);
  k_wnorm  <<<256, 256, 0, stream>>>(cw, wsq, wbt);
  k_dcoefs <<<16, 256, 0, stream>>>(styles, wsq, scal, dco);
  k_xpad   <<<dim3(4, 68, 16), 256, 0, stream>>>(x, styles, scal, xp);
  k_conv   <<<2180, 256, 0, stream>>>(xp, (const unsigned short*)wbt, dco, cb, y);
  k_lrelu  <<<16384, 256, 0, stream>>>(y, out, ft);
}

// Round 17
// 246.206 us; speedup vs baseline: 1.0077x; 1.0077x over previous
//
#include <hip/hip_runtime.h>
#include <hip/hip_bf16.h>
#include <math.h>

// StyleGAN3 SynthesisLayer forward, MI355X.
// B=16, CIN=COUT=256, H=W=64, K=3, up=2 down=2 taps=12, conv out 66x66,
// up-FIR out 138x138, final out 64x64.
//
// Final structure (session ledger):
//   k_conv : implicit GEMM, BM=128 x BN=64, 4 waves, 16x16x32 bf16 MFMA,
//            XCD-bijective block swizzle, launch_bounds(256,5) [R14 optimum:
//            118us; (256,6) and all deeper pipeline variants were null/worse].
//   k_lrelu: fp16 packed (v_pk_fma_f16) column-strip filtered-lrelu [R13].
//   absmax 0.0078 (threshold 0.041).

typedef __attribute__((ext_vector_type(8))) short bf16x8;
typedef __attribute__((ext_vector_type(4))) float f32x4;
typedef _Float16 h2 __attribute__((ext_vector_type(2)));

#define NM 69696         // 16*66*66 flattened conv-output positions
#define SPI 4356         // 66*66 spatial per image

__device__ inline void gload16(const void* g, void* l) {
  __builtin_amdgcn_global_load_lds((const __attribute__((address_space(1))) void*)g,
                                   (__attribute__((address_space(3))) void*)l, 16, 0, 0);
}
static __device__ __forceinline__ short f2hs(float f) {
  _Float16 h = (_Float16)f;
  return *(short*)&h;
}
static __device__ __forceinline__ h2 h2bc(unsigned u) { return __builtin_bit_cast(h2, u); }
static __device__ __forceinline__ unsigned u32bc(h2 v) { return __builtin_bit_cast(unsigned, v); }
static __device__ __forceinline__ h2 h2splat(float f) {
  _Float16 x = (_Float16)f; h2 r; r[0] = x; r[1] = x; return r;
}

// ---------- styles = w @ aw^T / sqrt(512) + ab ----------
__global__ __launch_bounds__(256) void k_styles(
    const float* __restrict__ w, const float* __restrict__ aw,
    const float* __restrict__ ab, float* __restrict__ styles) {
  __shared__ float lw[512];
  int b = blockIdx.x, t = threadIdx.x;
  lw[t] = w[b * 512 + t];
  lw[t + 256] = w[b * 512 + t + 256];
  __syncthreads();
  const float* row = aw + (long)t * 512;
  float acc = 0.f;
  #pragma unroll 4
  for (int d = 0; d < 512; ++d) acc += row[d] * lw[d];
  styles[b * 256 + t] = acc * 0.04419417382415922f + ab[t];
}

// ---------- scal[0] = 1/mean(styles^2), scal[1] = rsqrt(ema) ----------
__global__ __launch_bounds__(256) void k_scalars(
    const float* __restrict__ styles, const float* __restrict__ ema,
    float* __restrict__ scal) {
  __shared__ float red[256];
  int t = threadIdx.x;
  float s = 0.f;
  #pragma unroll
  for (int k = 0; k < 16; ++k) { float v = styles[t + k * 256]; s += v * v; }
  red[t] = s; __syncthreads();
  for (int off = 128; off > 0; off >>= 1) {
    if (t < off) red[t] += red[t + off];
    __syncthreads();
  }
  if (t == 0) { scal[0] = 4096.0f / red[0]; scal[1] = 1.0f / sqrtf(ema[0]); }
}

// ---------- per-o weight norm; wsq[o][i]; wbt[tap][o][i] bf16 ----------
__global__ __launch_bounds__(256) void k_wnorm(
    const float* __restrict__ cw, float* __restrict__ wsq,
    __hip_bfloat16* __restrict__ wbt) {
  __shared__ float red[256];
  __shared__ float lws, lws2;
  int o = blockIdx.x, t = threadIdx.x;
  const float* base = cw + o * 2304;
  float s = 0.f;
  #pragma unroll
  for (int k = 0; k < 9; ++k) { float v = base[t + k * 256]; s += v * v; }
  red[t] = s; __syncthreads();
  for (int off = 128; off > 0; off >>= 1) {
    if (t < off) red[t] += red[t + off];
    __syncthreads();
  }
  if (t == 0) { lws2 = 2304.0f / red[0]; lws = sqrtf(lws2); }
  __syncthreads();
  const float* r9 = base + t * 9;
  float s9 = 0.f;
  #pragma unroll
  for (int k = 0; k < 9; ++k) s9 += r9[k] * r9[k];
  wsq[o * 256 + t] = lws2 * s9;
  #pragma unroll
  for (int tap = 0; tap < 9; ++tap)
    wbt[(tap * 256 + o) * 256 + t] = __float2bfloat16(r9[tap] * lws);
}

// ---------- dcoefs[b][o] = rsqrt(sum_i s^2 * wsq + 1e-8) * input_gain ----------
__global__ __launch_bounds__(256) void k_dcoefs(
    const float* __restrict__ styles, const float* __restrict__ wsq,
    const float* __restrict__ scal, float* __restrict__ dco) {
  __shared__ float sn2[256];
  int b = blockIdx.x, t = threadIdx.x;
  float v = styles[b * 256 + t];
  sn2[t] = v * v * scal[0];
  __syncthreads();
  const float* wr = wsq + t * 256;
  float acc = 0.f;
  #pragma unroll 4
  for (int i = 0; i < 256; ++i) acc += sn2[i] * wr[i];
  dco[b * 256 + t] = (1.0f / sqrtf(acc + 1e-8f)) * scal[1];
}

// ---------- xs_pad[b][68][68][256] bf16, NHWC, style-scaled ----------
__global__ __launch_bounds__(256) void k_xpad(
    const float* __restrict__ x, const float* __restrict__ styles,
    const float* __restrict__ scal, unsigned short* __restrict__ xp) {
  __shared__ float lx[64 * 65];
  __shared__ float sc[64];
  int ig = blockIdx.x, hp = blockIdx.y, b = blockIdx.z, t = threadIdx.x;
  int i0 = ig * 64;
  float ss = sqrtf(scal[0]);
  if (t < 64) sc[t] = styles[b * 256 + i0 + t] * ss;
  int h = hp - 2;
  bool inh = (hp >= 2) && (hp < 66);
  if (inh) {
    #pragma unroll
    for (int p = 0; p < 16; ++p) {
      int idx = p * 256 + t; int i = idx >> 6, w = idx & 63;
      lx[i * 65 + w] = x[((b * 256 + i0 + i) * 64 + h) * 64 + w];
    }
  }
  __syncthreads();
  unsigned short* dst = xp + ((long)(b * 68 + hp) * 68) * 256 + i0;
  #pragma unroll
  for (int p = 0; p < 17; ++p) {
    int idx = p * 256 + t; int wp = idx >> 6, i = idx & 63;
    float v = 0.f;
    if (inh && wp >= 2 && wp < 66) v = lx[i * 65 + (wp - 2)] * sc[i];
    __hip_bfloat16 bv = __float2bfloat16(v);
    dst[wp * 256 + i] = *(unsigned short*)&bv;
  }
}

// ---------- conv v8 (final): BN=64, launch_bounds(256,5) ----------
// R15 A/B: (256,6) occupancy 48.8% vs (256,5) 42% -> dur flat/worse; 5 is
// the measured optimum. Structure at its LDS/latency floor (see ledger).
__global__ __launch_bounds__(256, 5) void k_conv(
    const unsigned short* __restrict__ xp, const unsigned short* __restrict__ wbt,
    const float* __restrict__ dco, const float* __restrict__ bias,
    unsigned short* __restrict__ y) {
  __shared__ __align__(16) unsigned short As[128 * 64];   // 16 KB
  __shared__ __align__(16) unsigned short Bs[64 * 64];    // 8 KB
  const int t = threadIdx.x;
  const int lane = t & 63;
  const int wave = t >> 6;
  const int wm = wave >> 1, wn = wave & 1;   // 2m x 2n

  // bijective XCD swizzle: nwg=2180 = 8*272 + 4 (xcd 0..3 get 273)
  const int f = blockIdx.x;
  const int xcd = f & 7, pos = f >> 3;
  const int wgid = (xcd < 4 ? xcd * 273 : 1092 + (xcd - 4) * 272) + pos;
  const int o0 = (wgid & 3) * 64;
  const int m0 = (wgid >> 2) * 128;

  // A staging: 1024 slots, 4/thread
  int abase[4];
  #pragma unroll
  for (int j = 0; j < 4; ++j) {
    int task = j * 256 + t;
    int lm = task >> 3, ch = task & 7;
    int csrc = ch ^ (lm & 7);
    int m = m0 + lm; if (m > NM - 1) m = NM - 1;
    int b = m / SPI; int sp = m - b * SPI;
    int r = sp / 66; int c = sp - r * 66;
    abase[j] = (((b * 68 + r) * 68 + c) << 9) + (csrc << 4);   // bytes
  }
  // B staging: 512 slots (64 o-rows x 8 chunks), 2/thread
  int bbase[2];
  #pragma unroll
  for (int j = 0; j < 2; ++j) {
    int task = j * 256 + t;
    int lm = task >> 3, ch = task & 7;
    int csrc = ch ^ (lm & 7);
    bbase[j] = ((o0 + lm) << 9) + (csrc << 4);                 // bytes
  }
  f32x4 acc[4][2] = {};
  const char* xb = (const char*)xp;
  const char* wb = (const char*)wbt;
  char* asb = (char*)As;
  char* bsb = (char*)Bs;

  for (int kk = 0; kk < 36; ++kk) {
    int tap = kk >> 2;
    int ch0b = (kk & 3) << 7;            // ch0 * 2 bytes
    int ky = tap / 3, kx = tap - ky * 3;
    int aoff = ((ky * 68 + kx) << 9) + ch0b;
    int boff = (tap << 17) + ch0b;
    #pragma unroll
    for (int j = 0; j < 4; ++j)
      gload16(xb + abase[j] + aoff, asb + ((j * 256 + t) << 4));
    #pragma unroll
    for (int j = 0; j < 2; ++j)
      gload16(wb + bbase[j] + boff, bsb + ((j * 256 + t) << 4));
    __syncthreads();   // drains vmcnt -> tiles visible
    #pragma unroll
    for (int h = 0; h < 2; ++h) {
      bf16x8 av[4], bv[2];
      #pragma unroll
      for (int fm = 0; fm < 4; ++fm) {
        int arow = wm * 64 + fm * 16 + (lane & 15);
        int chk = ((h << 2) + (lane >> 4)) ^ (arow & 7);
        av[fm] = *(const bf16x8*)(asb + arow * 128 + chk * 16);
      }
      #pragma unroll
      for (int fn = 0; fn < 2; ++fn) {
        int brow = wn * 32 + fn * 16 + (lane & 15);
        int chk = ((h << 2) + (lane >> 4)) ^ (brow & 7);
        bv[fn] = *(const bf16x8*)(bsb + brow * 128 + chk * 16);
      }
      #pragma unroll
      for (int fm = 0; fm < 4; ++fm)
        #pragma unroll
        for (int fn = 0; fn < 2; ++fn)
          acc[fm][fn] = __builtin_amdgcn_mfma_f32_16x16x32_bf16(
              av[fm], bv[fn], acc[fm][fn], 0, 0, 0);
    }
    __syncthreads();   // readers done before next overwrite
  }

  // Epilogue: scale + bias, transpose via LDS slab [128m][17], write NCHW fp16.
  float* slab = (float*)As;
  #pragma unroll
  for (int s = 0; s < 4; ++s) {
    if (wn == (s >> 1)) {
      const int sfn = s & 1;
      int ocol = lane & 15;
      int og = o0 + s * 16 + ocol;
      float bo = bias[og];
      #pragma unroll
      for (int fm = 0; fm < 4; ++fm) {
        #pragma unroll
        for (int j = 0; j < 4; ++j) {
          int lm = wm * 64 + fm * 16 + ((lane >> 4) << 2) + j;
          int m = m0 + lm;
          float v = acc[fm][sfn][j];
          if (m < NM) {
            int b = m / SPI;
            v = v * dco[b * 256 + og] + bo;
          }
          slab[lm * 17 + ocol] = v;
        }
      }
    }
    __syncthreads();
    int oc2 = t >> 4;
    int og2 = o0 + s * 16 + oc2;
    #pragma unroll
    for (int p = 0; p < 8; ++p) {
      int lm = (t & 15) + p * 16;
      int m = m0 + lm;
      if (m < NM) {
        int b = m / SPI; int sp = m - b * SPI;
        y[(long)(b * 256 + og2) * SPI + sp] =
            (unsigned short)f2hs(slab[lm * 17 + oc2]);
      }
    }
    __syncthreads();
  }
}

// ---------- filtered_lrelu v4b: fp16 packed datapath (R13, unchanged) ----------
struct Filt { float f[12]; };

__global__ __launch_bounds__(256) void k_lrelu(
    const unsigned short* __restrict__ y, float* __restrict__ out, Filt ft) {
  __shared__ __align__(16) short t1s[138 * 40];   // 11040 B
  __shared__ __align__(16) short t2s[138 * 56];   // 15456 B
  short* bufYs = t2s;                             // [78][56]
  short* t3s = t1s;                               // [64][56]
  const int t = threadIdx.x;
  const int strip = blockIdx.x & 3;
  const long img = blockIdx.x >> 2;
  const int c0 = strip * 16;
  const unsigned short* ysrc = y + img * SPI;

  const h2 z2 = h2splat(0.f);
  h2 e2[6], o2[6], c3[6], c4[12];
  #pragma unroll
  for (int j = 0; j < 6; ++j) {
    e2[j] = h2splat(2.f * ft.f[2 * j]);
    o2[j] = h2splat(2.f * ft.f[2 * j + 1]);
    h2 c; c[0] = (_Float16)(2.f * ft.f[2 * j + 1]); c[1] = (_Float16)(2.f * ft.f[2 * j]);
    c3[j] = c;
  }
  #pragma unroll
  for (int j = 0; j < 12; ++j) c4[j] = h2splat(ft.f[j]);
  const h2 k02 = h2splat(0.2f);
  const h2 ks2 = h2splat(1.41421356237f);
  const h2 kpc = h2splat(256.f);
  const h2 knc = h2splat(-256.f);

  // phase 1: bufY [78][56] fp16; rows 6..71 = y rows 0..65; cols c0-4..c0+21
  #pragma unroll
  for (int p = 0; p < 2; ++p) {
    int e = p * 256 + t;
    if (e < 312) {
      int rp = e >> 2, cg = e & 3;
      int r = rp - 6;
      int cbase = c0 - 4 + 8 * cg;
      uint4 pk = make_uint4(0u, 0u, 0u, 0u);
      if (r >= 0 && r < 66) {
        if (cg < 3 && cbase >= 0 && cbase + 7 <= 65) {
          pk = *(const uint4*)(ysrc + r * 66 + cbase);
        } else {
          unsigned v[8];
          #pragma unroll
          for (int k = 0; k < 8; ++k) {
            int lc = 8 * cg + k, c = c0 - 4 + lc;
            v[k] = (lc < 26 && c >= 0 && c < 66) ? (unsigned)ysrc[r * 66 + c] : 0u;
          }
          pk.x = v[0] | (v[1] << 16); pk.y = v[2] | (v[3] << 16);
          pk.z = v[4] | (v[5] << 16); pk.w = v[6] | (v[7] << 16);
        }
      }
      *(uint4*)(bufYs + rp * 56 + 8 * cg) = pk;
    }
  }
  __syncthreads();

  // phase 2: vertical up-FIR, row pairs -> t1 [138][40]
  #pragma unroll
  for (int p = 0; p < 2; ++p) {
    int e = p * 256 + t;
    if (e < 276) {
      int rq = e >> 2, cg = e & 3;
      const short* base = bufYs + (rq + 2) * 56 + 8 * cg;
      h2 a0[4], a1[4];
      #pragma unroll
      for (int k = 0; k < 4; ++k) { a0[k] = z2; a1[k] = z2; }
      #pragma unroll
      for (int j = 0; j < 6; ++j) {
        uint4 u = *(const uint4*)(base + j * 56);
        h2 v0 = h2bc(u.x), v1 = h2bc(u.y), v2 = h2bc(u.z), v3 = h2bc(u.w);
        a0[0] = v0 * o2[j] + a0[0]; a1[0] = v0 * e2[j] + a1[0];
        a0[1] = v1 * o2[j] + a0[1]; a1[1] = v1 * e2[j] + a1[1];
        a0[2] = v2 * o2[j] + a0[2]; a1[2] = v2 * e2[j] + a1[2];
        a0[3] = v3 * o2[j] + a0[3]; a1[3] = v3 * e2[j] + a1[3];
      }
      uint4 s0, s1;
      s0.x = u32bc(a0[0]); s0.y = u32bc(a0[1]); s0.z = u32bc(a0[2]); s0.w = u32bc(a0[3]);
      s1.x = u32bc(a1[0]); s1.y = u32bc(a1[1]); s1.z = u32bc(a1[2]); s1.w = u32bc(a1[3]);
      *(uint4*)(t1s + (2 * rq) * 40 + 8 * cg) = s0;
      *(uint4*)(t1s + (2 * rq + 1) * 40 + 8 * cg) = s1;
    }
  }
  __syncthreads();

  // phase 3: horizontal up-FIR + lrelu*sqrt2 + clamp -> t2 [138][56]
  #pragma unroll
  for (int p = 0; p < 4; ++p) {
    int e = p * 256 + t;
    if (e < 828) {
      int rr = e / 6, g = e - rr * 6;
      const short* tr = t1s + rr * 40 + 4 * g;
      h2 h[5];
      #pragma unroll
      for (int q = 0; q < 5; ++q) h[q] = h2bc(*(const unsigned*)(tr + 2 * q));
      h2 r[4];
      #pragma unroll
      for (int i = 0; i < 4; ++i) {
        h2 a = z2;
        #pragma unroll
        for (int j = 0; j < 6; ++j) {
          int k = i + j;
          h2 src = h[k >> 1];
          h2 wb = (k & 1) ? __builtin_shufflevector(src, src, 1, 1)
                          : __builtin_shufflevector(src, src, 0, 0);
          a = wb * c3[j] + a;
        }
        h2 m = __builtin_elementwise_max(a, a * k02);
        m = m * ks2;
        m = __builtin_elementwise_min(__builtin_elementwise_max(m, knc), kpc);
        r[i] = m;
      }
      uint4 s;
      s.x = u32bc(r[0]); s.y = u32bc(r[1]); s.z = u32bc(r[2]); s.w = u32bc(r[3]);
      *(uint4*)(t2s + rr * 56 + 8 * g) = s;
    }
  }
  __syncthreads();

  // phase 4: vertical down-FIR (stride 2) -> t3 [64][56]
  #pragma unroll
  for (int p = 0; p < 2; ++p) {
    int e = p * 256 + t;
    if (e < 384) {
      int pp = e / 6, cg = e - pp * 6;
      const short* col = t2s + (2 * pp) * 56 + 8 * cg;
      h2 a[4];
      #pragma unroll
      for (int k = 0; k < 4; ++k) a[k] = z2;
      #pragma unroll
      for (int j = 0; j < 12; ++j) {
        uint4 u = *(const uint4*)(col + j * 56);
        a[0] = h2bc(u.x) * c4[j] + a[0];
        a[1] = h2bc(u.y) * c4[j] + a[1];
        a[2] = h2bc(u.z) * c4[j] + a[2];
        a[3] = h2bc(u.w) * c4[j] + a[3];
      }
      uint4 s;
      s.x = u32bc(a[0]); s.y = u32bc(a[1]); s.z = u32bc(a[2]); s.w = u32bc(a[3]);
      *(uint4*)(t3s + pp * 56 + 8 * cg) = s;
    }
  }
  __syncthreads();

  // phase 5: horizontal down-FIR (stride 2) + store f32, 4 outs/thread
  {
    int pp = t >> 2, v = t & 3;
    const short* row = t3s + pp * 56 + 8 * v;
    h2 h[9];
    #pragma unroll
    for (int q = 0; q < 9; ++q) h[q] = h2bc(*(const unsigned*)(row + 2 * q));
    h2 aA = z2, aB = z2;
    #pragma unroll
    for (int j = 0; j < 12; ++j) {
      int q = j >> 1;
      h2 wA = (j & 1) ? __builtin_shufflevector(h[q], h[q + 1], 1, 3)
                      : __builtin_shufflevector(h[q], h[q + 1], 0, 2);
      h2 wB = (j & 1) ? __builtin_shufflevector(h[q + 2], h[q + 3], 1, 3)
                      : __builtin_shufflevector(h[q + 2], h[q + 3], 0, 2);
      aA = wA * c4[j] + aA;
      aB = wB * c4[j] + aB;
    }
    *(float4*)&out[img * 4096 + pp * 64 + c0 + 4 * v] =
        make_float4((float)aA[0], (float)aA[1], (float)aB[0], (float)aB[1]);
  }
}

// ---------- host ----------
static double bessel_i0(double x) {
  double q = x * x * 0.25, term = 1.0, sum = 1.0;
  for (int k = 1; k < 64; ++k) {
    term *= q / ((double)k * (double)k);
    sum += term;
    if (term < sum * 1e-18) break;
  }
  return sum;
}

extern "C" void kernel_launch(void* const* d_in, const int* in_sizes, int n_in,
                              void* d_out, int out_size, void* d_ws, size_t ws_size,
                              hipStream_t stream) {
  const float* x   = (const float*)d_in[0];
  const float* w   = (const float*)d_in[1];
  const float* aw  = (const float*)d_in[2];
  const float* ab  = (const float*)d_in[3];
  const float* cw  = (const float*)d_in[4];
  const float* cb  = (const float*)d_in[5];
  const float* ema = (const float*)d_in[6];
  float* out = (float*)d_out;
  char* ws = (char*)d_ws;

  float* styles        = (float*)(ws + 0);          // 16 KB
  float* scal          = (float*)(ws + 16384);      // 16 B
  float* wsq           = (float*)(ws + 16640);      // 256 KB
  float* dco           = (float*)(ws + 278784);     // 16 KB
  __hip_bfloat16* wbt  = (__hip_bfloat16*)(ws + 295168);   // 1.18 MB  [9][256][256]
  unsigned short* xp   = (unsigned short*)(ws + 1474816);  // 37.9 MB  [16][68][68][256]
  unsigned short* y    = (unsigned short*)(ws + 39354624); // 35.7 MB  [16][256][66][66] fp16

  // firwin(12, 16, width=32, fs=128) with Kaiser window (double precision)
  Filt ft;
  {
    double atten = 2.285 * 11.0 * M_PI * 0.5 + 7.95;
    double beta;
    if (atten > 50.0) beta = 0.1102 * (atten - 8.7);
    else if (atten > 21.0) beta = 0.5842 * pow(atten - 21.0, 0.4) + 0.07886 * (atten - 21.0);
    else beta = 0.0;
    double i0b = bessel_i0(beta);
    double h[12], ssum = 0.0;
    for (int n = 0; n < 12; ++n) {
      double xx = ((double)n - 5.5) / 5.5;
      double win = bessel_i0(beta * sqrt(1.0 - xx * xx)) / i0b;
      double mm = ((double)n - 5.5) * 0.25;
      double snc = sin(M_PI * mm) / (M_PI * mm);
      h[n] = 0.25 * snc * win;
      ssum += h[n];
    }
    for (int n = 0; n < 12; ++n) ft.f[n] = (float)(h[n] / ssum);
  }

  k_styles <<<16, 256, 0, stream>>>(w, aw, ab, styles);
  k_scalars<<<1, 256, 0, stream>>>(styles, ema, scal);
  k_wnorm  <<<256, 256, 0, stream>>>(cw, wsq, wbt);
  k_dcoefs <<<16, 256, 0, stream>>>(styles, wsq, scal, dco);
  k_xpad   <<<dim3(4, 68, 16), 256, 0, stream>>>(x, styles, scal, xp);
  k_conv   <<<2180, 256, 0, stream>>>(xp, (const unsigned short*)wbt, dco, cb, y);
  k_lrelu  <<<16384, 256, 0, stream>>>(y, out, ft);
}